// Round 10
// baseline (69.323 us; speedup 1.0000x reference)
//
#include <hip/hip_runtime.h>
#include <math.h>

typedef __attribute__((ext_vector_type(8))) __bf16 b16x8;
typedef __attribute__((ext_vector_type(4))) float f32x4;

__device__ __forceinline__ unsigned short f2bf(float x) {
    unsigned int v = __float_as_uint(x);
    v += 0x7fffu + ((v >> 16) & 1u);
    return (unsigned short)(v >> 16);
}

// 16-lane sum reduction entirely on the VALU via DPP (no LDS pipe).
__device__ __forceinline__ float red16(float x) {
    int v;
    v = __builtin_amdgcn_update_dpp(0, __float_as_int(x), 0xB1, 0xF, 0xF, true);
    x += __int_as_float(v);
    v = __builtin_amdgcn_update_dpp(0, __float_as_int(x), 0x4E, 0xF, 0xF, true);
    x += __int_as_float(v);
    v = __builtin_amdgcn_update_dpp(0, __float_as_int(x), 0x141, 0xF, 0xF, true);
    x += __int_as_float(v);
    v = __builtin_amdgcn_update_dpp(0, __float_as_int(x), 0x140, 0xF, 0xF, true);
    x += __int_as_float(v);
    return x;
}

// ---------------- repack kernel ----------------
// ws layout: [0, 819200): weights bf16, PER-WAVE-CONTIGUOUS, visit order:
//   slot l = kw*10 + ks*5 + kh   (conv tap = kh*5+kw, cin plane ks)
//   idx = (((l*4 + wn)*4 + fr)*64 + lane)*8 + j     (ushort index)
//   value = W[cin = ks*32 + (lane>>4)*8 + j][o = wn*64 + fr*16 + (lane&15)]
//   -> each (l,wn,fr) is a 1KB contiguous chunk = one coalesced dwordx4/wave.
// [819200, 820224): bias_sum fp32 [256]
__global__ __launch_bounds__(256) void repack_w(
    const float* __restrict__ Wt, const float* __restrict__ bias,
    unsigned short* __restrict__ wsw, float* __restrict__ wsb) {
    int idx = blockIdx.x * 256 + threadIdx.x;
    if (idx < 409600) {
        int j    = idx & 7;
        int lane = (idx >> 3) & 63;
        int fr   = (idx >> 9) & 3;
        int wn   = (idx >> 11) & 3;
        int l    = idx >> 13;          // visit slot 0..49
        int kh   = l % 5;
        int ks   = (l / 5) & 1;
        int kw   = l / 10;
        int tap  = kh * 5 + kw;
        int col  = lane & 15;
        int cg   = lane >> 4;
        int o    = wn * 64 + fr * 16 + col;
        int cin  = ks * 32 + cg * 8 + j;
        int ic = cin >> 4, id = cin & 15;
        float w = Wt[((size_t)(ic * 256 + o) * 16 + id) * 25 + tap];
        wsw[idx] = f2bf(w);
    } else if (idx < 409856) {
        int o = idx - 409600;
        float s = 0.f;
        for (int ic = 0; ic < 4; ++ic) s += bias[ic * 256 + o];
        wsb[o] = s;
    }
}

// ---------------- main kernel ----------------
// Block: 1024 threads (16 waves) = one 16x16 spatial tile x all 256 outputs.
// Wave tile: 64 pix x 64 outs = 4 pixfrags x 4 ofrags (16x16x32 MFMA).
// ZERO barriers after the prologue: weights are loaded DIRECTLY from global
// (L2/L1-resident, per-wave-contiguous 1KB dwordx4 loads) into registers with
// a 1-iteration software double-buffer (bfA/bfB); su_sh (u halo, 51.2KB LDS)
// is read-only after staging. Waves run fully decoupled, so ds-read / MFMA /
// VMEM phases of the 4 waves/SIMD self-interleave and early waves overlap
// their epilogue stores with late waves' compute.
__global__ __launch_bounds__(1024, 4) void caps_mfma(
    const float* __restrict__ u, const unsigned short* __restrict__ wsw,
    const float* __restrict__ wsb, float* __restrict__ out) {

    __shared__ __align__(16) unsigned short su_sh[25600];   // 2 planes x [hy20][hx20][cgp4][j8]

    const int tid  = threadIdx.x;
    const int lane = tid & 63;
    const int wid  = tid >> 6;      // 0..15
    const int wm   = wid >> 2;      // 0..3  pixel-row-group (4 rows each)
    const int wn   = wid & 3;       // 0..3  output-col-group (64 outs each)
    const int col  = lane & 15;
    const int cg   = lane >> 4;     // 0..3  cin-group (and x-group in C layout)
    const int ybase = wm * 4;
    const int obase = wn * 64;

    const int bx  = blockIdx.x;     // 0..63
    const int b   = blockIdx.y;     // 0..3
    const int ty0 = (bx >> 3) * 16;
    const int tx0 = (bx & 7) * 16;

    // A-frag column offsets per kw (ushort index within a row cell)
    int coffs[5];
    #pragma unroll
    for (int kw = 0; kw < 5; ++kw) {
        int hx = col + kw;
        coffs[kw] = hx * 32 + ((cg ^ ((hx >> 1) & 3)) * 8);
    }

    f32x4 acc[4][4];
    #pragma unroll
    for (int f = 0; f < 4; ++f)
        #pragma unroll
        for (int fr = 0; fr < 4; ++fr) acc[f][fr] = (f32x4)0.f;

    auto stage_u = [&](int half) {
        const float* up = u + ((size_t)b * 64 + half * 32) * 16384;
        unsigned short* dstp = su_sh + half * 12800;
        #pragma unroll 1
        for (int i = tid; i < 12800; i += 1024) {
            int c = i / 400;                    // cin local 0..31
            int s = i - c * 400;
            int hy = s / 20, hx = s - hy * 20;  // halo coords 0..19
            int gy = ty0 - 2 + hy, gx = tx0 - 2 + hx;
            float v = 0.f;
            if ((unsigned)gy < 128u && (unsigned)gx < 128u)
                v = up[(size_t)c * 16384 + gy * 128 + gx];
            int cgp = (c >> 3) ^ ((hx >> 1) & 3);
            dstp[(hy * 20 + hx) * 32 + cgp * 8 + (c & 7)] = f2bf(v);
        }
    };

    // per-wave weight base: slot stride 16384B, [wn]4096B, [fr]1024B, lane*16B
    const char* wp0 = ((const char*)wsw) + wn * 4096 + lane * 16;
    auto loadB = [&](int slot, b16x8* bf) {
        const char* p = wp0 + (size_t)slot * 16384;
        bf[0] = *reinterpret_cast<const b16x8*>(p);
        bf[1] = *reinterpret_cast<const b16x8*>(p + 1024);
        bf[2] = *reinterpret_cast<const b16x8*>(p + 2048);
        bf[3] = *reinterpret_cast<const b16x8*>(p + 3072);
    };

    // prologue
    b16x8 bfA[4], bfB[4];
    loadB(0, bfA);
    stage_u(0);
    stage_u(1);
    __syncthreads();               // su_sh stable from here on; no more barriers

    #pragma unroll 1
    for (int g = 0; g < 5; ++g) {                  // g == kw
        const unsigned short* base0 = su_sh + ybase * 640 + coffs[g];
        const int l0 = g * 10;

#define COMP(I, BF)                                                            \
        {                                                                      \
            const unsigned short* ap = base0 + ((I) / 5) * 12800               \
                                             + ((I) % 5) * 640;                \
            b16x8 a0 = *reinterpret_cast<const b16x8*>(ap);                    \
            b16x8 a1 = *reinterpret_cast<const b16x8*>(ap + 640);              \
            b16x8 a2 = *reinterpret_cast<const b16x8*>(ap + 1280);             \
            b16x8 a3 = *reinterpret_cast<const b16x8*>(ap + 1920);             \
            __builtin_amdgcn_s_setprio(1);                                     \
            _Pragma("unroll")                                                  \
            for (int fr = 0; fr < 4; ++fr) {                                   \
                acc[0][fr] = __builtin_amdgcn_mfma_f32_16x16x32_bf16(          \
                    a0, BF[fr], acc[0][fr], 0, 0, 0);                          \
                acc[1][fr] = __builtin_amdgcn_mfma_f32_16x16x32_bf16(          \
                    a1, BF[fr], acc[1][fr], 0, 0, 0);                          \
                acc[2][fr] = __builtin_amdgcn_mfma_f32_16x16x32_bf16(          \
                    a2, BF[fr], acc[2][fr], 0, 0, 0);                          \
                acc[3][fr] = __builtin_amdgcn_mfma_f32_16x16x32_bf16(          \
                    a3, BF[fr], acc[3][fr], 0, 0, 0);                          \
            }                                                                  \
            __builtin_amdgcn_s_setprio(0);                                     \
        }
#define STEP2(I)                                                               \
        loadB((l0 + (I) + 1 > 49) ? 49 : l0 + (I) + 1, bfB);                   \
        COMP(I, bfA)                                                           \
        loadB((l0 + (I) + 2 > 49) ? 49 : l0 + (I) + 2, bfA);                   \
        COMP((I) + 1, bfB)

        STEP2(0) STEP2(2) STEP2(4) STEP2(6) STEP2(8)
#undef STEP2
#undef COMP
    }

    // ---------------- epilogue: bias + r-scale + squash (DPP) + float4 store --
    float bsv[4];
    #pragma unroll
    for (int fr = 0; fr < 4; ++fr) bsv[fr] = wsb[obase + fr * 16 + col];

    const int xg = lane >> 4;   // x-group in C layout
    #pragma unroll
    for (int f = 0; f < 4; ++f) {
        int h = ty0 + ybase + f;
        int rows = min(h + 2, 127) - max(h - 2, 0) + 1;
        #pragma unroll
        for (int p = 0; p < 2; ++p) {
            int oc = wn * 2 + p;
            float o0[4], o1[4];
            #pragma unroll
            for (int r = 0; r < 4; ++r) {
                int w = tx0 + xg * 4 + r;
                int colsv = min(w + 2, 127) - max(w - 2, 0) + 1;
                float rs = 1.0f / (8.0f * (float)(rows * colsv));
                float p0 = (acc[f][2 * p][r] + bsv[2 * p]) * rs;
                float p1 = (acc[f][2 * p + 1][r] + bsv[2 * p + 1]) * rs;
                o0[r] = p0; o1[r] = p1;
                float sv = red16(p0 * p0 + p1 * p1);
                float scale = sv / ((1.0f + sv) * sqrtf(sv + 1e-9f));
                o0[r] *= scale; o1[r] *= scale;
            }
            size_t base = ((size_t)((b * 8 + oc) * 32) + col) * 16384
                          + (size_t)h * 128 + tx0 + xg * 4;
            float4 v0 = make_float4(o0[0], o0[1], o0[2], o0[3]);
            float4 v1 = make_float4(o1[0], o1[1], o1[2], o1[3]);
            *reinterpret_cast<float4*>(out + base) = v0;
            *reinterpret_cast<float4*>(out + base + (size_t)16 * 16384) = v1;
        }
    }
}

extern "C" void kernel_launch(void* const* d_in, const int* in_sizes, int n_in,
                              void* d_out, int out_size, void* d_ws, size_t ws_size,
                              hipStream_t stream) {
    const float* u    = (const float*)d_in[0];
    const float* Wt   = (const float*)d_in[1];
    const float* bias = (const float*)d_in[2];
    unsigned short* wsw = (unsigned short*)d_ws;
    float* wsb = (float*)((char*)d_ws + 819200);

    repack_w<<<1601, 256, 0, stream>>>(Wt, bias, wsw, wsb);
    caps_mfma<<<dim3(64, 4), 1024, 0, stream>>>(u, wsw, wsb, (float*)d_out);
}

// Round 12
// 65.047 us; speedup vs baseline: 1.0657x; 1.0657x over previous
//
#include <hip/hip_runtime.h>
#include <math.h>

typedef __attribute__((ext_vector_type(8))) __bf16 b16x8;
typedef __attribute__((ext_vector_type(4))) float f32x4;

__device__ __forceinline__ unsigned short f2bf(float x) {
    unsigned int v = __float_as_uint(x);
    v += 0x7fffu + ((v >> 16) & 1u);
    return (unsigned short)(v >> 16);
}

// 16-lane sum reduction entirely on the VALU via DPP (no LDS pipe).
__device__ __forceinline__ float red16(float x) {
    int v;
    v = __builtin_amdgcn_update_dpp(0, __float_as_int(x), 0xB1, 0xF, 0xF, true);
    x += __int_as_float(v);
    v = __builtin_amdgcn_update_dpp(0, __float_as_int(x), 0x4E, 0xF, 0xF, true);
    x += __int_as_float(v);
    v = __builtin_amdgcn_update_dpp(0, __float_as_int(x), 0x141, 0xF, 0xF, true);
    x += __int_as_float(v);
    v = __builtin_amdgcn_update_dpp(0, __float_as_int(x), 0x140, 0xF, 0xF, true);
    x += __int_as_float(v);
    return x;
}

// ---------------- repack kernel ----------------
// ws layout: [0, 819200): weights bf16, PER-WAVE-CONTIGUOUS, visit order:
//   slot l = kw*10 + ks*5 + kh   (conv tap = kh*5+kw, cin plane ks)
//   idx = (((l*8 + wn)*2 + fr)*64 + lane)*8 + j     (ushort index)
//   value = W[cin = ks*32 + (lane>>4)*8 + j][o = wn*32 + fr*16 + (lane&15)]
//   -> each (l,wn,fr) is a 1KB contiguous chunk = one coalesced dwordx4/wave.
// [819200, 820224): bias_sum fp32 [256]
__global__ __launch_bounds__(256) void repack_w(
    const float* __restrict__ Wt, const float* __restrict__ bias,
    unsigned short* __restrict__ wsw, float* __restrict__ wsb) {
    int idx = blockIdx.x * 256 + threadIdx.x;
    if (idx < 409600) {
        int j    = idx & 7;
        int lane = (idx >> 3) & 63;
        int fr   = (idx >> 9) & 1;
        int wn   = (idx >> 10) & 7;
        int l    = idx >> 13;          // visit slot 0..49
        int kh   = l % 5;
        int ks   = (l / 5) & 1;
        int kw   = l / 10;
        int tap  = kh * 5 + kw;
        int col  = lane & 15;
        int cg   = lane >> 4;
        int o    = wn * 32 + fr * 16 + col;
        int cin  = ks * 32 + cg * 8 + j;
        int ic = cin >> 4, id = cin & 15;
        float w = Wt[((size_t)(ic * 256 + o) * 16 + id) * 25 + tap];
        wsw[idx] = f2bf(w);
    } else if (idx < 409856) {
        int o = idx - 409600;
        float s = 0.f;
        for (int ic = 0; ic < 4; ++ic) s += bias[ic * 256 + o];
        wsb[o] = s;
    }
}

// ---------------- main kernel ----------------
// Block: 1024 threads (16 waves) = one 16x16 spatial tile x all 256 outputs.
// Wave tile: 128 px x 32 outs = 8 pixfrags x 2 ofrags (16x16x32 MFMA),
// acc = 64 VGPR. This aspect ratio HALVES B-operand traffic vs 64x64:
// 2KB/wave/slot from L2 (2x redundancy) and one wave owns exactly one
// capsule (squash fully wave-local).
// A-frags: 8-deep CIRCULAR register row-window per (kw,ks). Invariant at
// step kh: aw[i] = row i (i>=kh) / row i+8 (i<kh); MFMA f uses aw[(kh+f)&7]
// = row kh+f. The slide (row kh+8 -> aw[kh&7]) happens AFTER cluster kh
// (its last reader is f=0 of cluster kh; next reader is f=7 of cluster
// kh+1, leaving ~1 cluster of latency cover).  [R11 bug: slide was
// pre-cluster, clobbering the live row -> absmax 9.5e-3.]
// ZERO barriers after the prologue; weights stream directly L2->VGPR with
// a distance-1 ping-pong (2 dwordx4/slot).
__global__ __launch_bounds__(1024, 4) void caps_mfma(
    const float* __restrict__ u, const unsigned short* __restrict__ wsw,
    const float* __restrict__ wsb, float* __restrict__ out) {

    __shared__ __align__(16) unsigned short su_sh[25600];   // 2 planes x [hy20][hx20][cgp4][j8]

    const int tid  = threadIdx.x;
    const int lane = tid & 63;
    const int wid  = tid >> 6;      // 0..15
    const int wm   = wid >> 3;      // 0..1  pixel-row-group (8 rows each)
    const int wn   = wid & 7;       // 0..7  capsule (32 outs each)
    const int col  = lane & 15;
    const int cg   = lane >> 4;     // 0..3  cin-group (and x-group in C layout)
    const int ybase = wm * 8;

    const int bx  = blockIdx.x;     // 0..63
    const int b   = blockIdx.y;     // 0..3
    const int ty0 = (bx >> 3) * 16;
    const int tx0 = (bx & 7) * 16;

    f32x4 acc[8][2];
    #pragma unroll
    for (int f = 0; f < 8; ++f) {
        acc[f][0] = (f32x4)0.f;
        acc[f][1] = (f32x4)0.f;
    }

    auto stage_u = [&](int half) {
        const float* up = u + ((size_t)b * 64 + half * 32) * 16384;
        unsigned short* dstp = su_sh + half * 12800;
        #pragma unroll 1
        for (int i = tid; i < 12800; i += 1024) {
            int c = i / 400;                    // cin local 0..31
            int s = i - c * 400;
            int hy = s / 20, hx = s - hy * 20;  // halo coords 0..19
            int gy = ty0 - 2 + hy, gx = tx0 - 2 + hx;
            float v = 0.f;
            if ((unsigned)gy < 128u && (unsigned)gx < 128u)
                v = up[(size_t)c * 16384 + gy * 128 + gx];
            int cgp = (c >> 3) ^ ((hx >> 1) & 3);
            dstp[(hy * 20 + hx) * 32 + cgp * 8 + (c & 7)] = f2bf(v);
        }
    };

    // per-wave weight base: slot stride 16384B, [wn]2048B, [fr]1024B, lane*16B
    const char* wp0 = ((const char*)wsw) + wn * 2048 + lane * 16;
    auto loadB = [&](int slot, b16x8* bf) {
        const char* p = wp0 + (size_t)slot * 16384;
        bf[0] = *reinterpret_cast<const b16x8*>(p);
        bf[1] = *reinterpret_cast<const b16x8*>(p + 1024);
    };

    // prologue
    b16x8 bfA[2], bfB[2];
    loadB(0, bfA);
    stage_u(0);
    stage_u(1);
    __syncthreads();               // su_sh stable from here on; no more barriers

    #pragma unroll 1
    for (int g = 0; g < 5; ++g) {                  // g == kw
        const int hx   = col + g;
        const int coff = hx * 32 + ((cg ^ ((hx >> 1) & 3)) * 8);
        const int l0   = g * 10;
        #pragma unroll
        for (int ks = 0; ks < 2; ++ks) {
            // base of this plane's halo rows for this wave (row stride 640)
            const unsigned short* apb =
                su_sh + ks * 12800 + ybase * 640 + coff;

            // init circular A-window: rows 0..7 (relative to ybase)
            b16x8 aw[8];
            #pragma unroll
            for (int i = 0; i < 8; ++i)
                aw[i] = *reinterpret_cast<const b16x8*>(apb + i * 640);

            #pragma unroll
            for (int kh = 0; kh < 5; ++kh) {
                const int l  = l0 + ks * 5 + kh;
                const int ln = (l + 1 > 49) ? 49 : l + 1;
                b16x8* cur = ((ks * 5 + kh) & 1) ? bfB : bfA;
                b16x8* nxt = ((ks * 5 + kh) & 1) ? bfA : bfB;

                loadB(ln, nxt);                     // next slot's B (dist-1)

                __builtin_amdgcn_s_setprio(1);
                #pragma unroll
                for (int f = 0; f < 8; ++f) {
                    acc[f][0] = __builtin_amdgcn_mfma_f32_16x16x32_bf16(
                        aw[(kh + f) & 7], cur[0], acc[f][0], 0, 0, 0);
                    acc[f][1] = __builtin_amdgcn_mfma_f32_16x16x32_bf16(
                        aw[(kh + f) & 7], cur[1], acc[f][1], 0, 0, 0);
                }
                __builtin_amdgcn_s_setprio(0);

                if (kh < 4)                         // slide AFTER cluster kh:
                    aw[kh & 7] = *reinterpret_cast<const b16x8*>(
                        apb + (kh + 8) * 640);      // row kh+8 replaces row kh
            }
        }
    }

    // ---------------- epilogue: bias + r-scale + squash (DPP) + float4 store --
    float bsv0 = wsb[wn * 32 + col];
    float bsv1 = wsb[wn * 32 + 16 + col];

    const int xg = lane >> 4;   // x-group in C layout
    #pragma unroll
    for (int f = 0; f < 8; ++f) {
        int h = ty0 + ybase + f;
        int rows = min(h + 2, 127) - max(h - 2, 0) + 1;
        float o0[4], o1[4];
        #pragma unroll
        for (int r = 0; r < 4; ++r) {
            int w = tx0 + xg * 4 + r;
            int colsv = min(w + 2, 127) - max(w - 2, 0) + 1;
            float rs = 1.0f / (8.0f * (float)(rows * colsv));
            float p0 = (acc[f][0][r] + bsv0) * rs;
            float p1 = (acc[f][1][r] + bsv1) * rs;
            o0[r] = p0; o1[r] = p1;
            float sv = red16(p0 * p0 + p1 * p1);
            float scale = sv / ((1.0f + sv) * sqrtf(sv + 1e-9f));
            o0[r] *= scale; o1[r] *= scale;
        }
        size_t base = ((size_t)((b * 8 + wn) * 32) + col) * 16384
                      + (size_t)h * 128 + tx0 + xg * 4;
        float4 v0 = make_float4(o0[0], o0[1], o0[2], o0[3]);
        float4 v1 = make_float4(o1[0], o1[1], o1[2], o1[3]);
        *reinterpret_cast<float4*>(out + base) = v0;
        *reinterpret_cast<float4*>(out + base + (size_t)16 * 16384) = v1;
    }
}

extern "C" void kernel_launch(void* const* d_in, const int* in_sizes, int n_in,
                              void* d_out, int out_size, void* d_ws, size_t ws_size,
                              hipStream_t stream) {
    const float* u    = (const float*)d_in[0];
    const float* Wt   = (const float*)d_in[1];
    const float* bias = (const float*)d_in[2];
    unsigned short* wsw = (unsigned short*)d_ws;
    float* wsb = (float*)((char*)d_ws + 819200);

    repack_w<<<1601, 256, 0, stream>>>(Wt, bias, wsw, wsb);
    caps_mfma<<<dim3(64, 4), 1024, 0, stream>>>(u, wsw, wsb, (float*)d_out);
}